// Round 1
// baseline (477.368 us; speedup 1.0000x reference)
//
#include <hip/hip_runtime.h>
#include <hip/hip_bf16.h>
#include <cstdint>

#define NC 28
#define HW 65536   // 256*256
#define ROWW 256
#define COLW 310
#define BATCH 16

typedef __hip_bfloat16 bf16;

// ---------------- K0: prep — transpose w1 matrices, compute alpha ----------------
__global__ void k0_prep(const float* __restrict__ w1mm, const float* __restrict__ w1pv,
                        float* __restrict__ hdr)
{
    int t = threadIdx.x;
    for (int e = t; e < 784; e += blockDim.x) {
        int c = e / 28, o = e - c * 28;
        hdr[e]       = w1mm[o * 28 + c];   // w1t_mm[c][o]
        hdr[784 + e] = w1pv[o * 28 + c];   // w1t_pv[c][o]
    }
    for (int col = t; col < COLW; col += blockDim.x) {
        int imin = (col > 255) ? ((col - 254) >> 1) : 0;
        int imax = min(27, col >> 1);
        hdr[1568 + col] = 1.0f / (float)(imax - imin + 1);
    }
}

// ---------------- K1: conv1x1 x2 for both branches, thread per pixel ----------------
__global__ void k1_conv1x1(const float* __restrict__ Phi,
                           const float* __restrict__ w2mm, const float* __restrict__ w2pv,
                           const float* __restrict__ b1mm, const float* __restrict__ b2mm,
                           const float* __restrict__ b1pv, const float* __restrict__ b2pv,
                           const float* __restrict__ hdr,
                           bf16* __restrict__ t_mm, bf16* __restrict__ t_pv,
                           bf16* __restrict__ m1_mm, bf16* __restrict__ m1_pv)
{
    int idx = blockIdx.x * 256 + threadIdx.x;   // 0 .. 1048575
    int b  = idx >> 16;                          // HW = 2^16
    int hw = idx & (HW - 1);
    const float* phi = Phi + (size_t)b * NC * HW + hw;

    float m1m[NC], m1p[NC];
#pragma unroll
    for (int o = 0; o < NC; o++) { m1m[o] = b1mm[o]; m1p[o] = b1pv[o]; }

    for (int c = 0; c < NC; c++) {
        float p = phi[(size_t)c * HW];
        const float* w1tm = hdr + c * NC;
        const float* w1tp = hdr + 784 + c * NC;
#pragma unroll
        for (int o = 0; o < NC; o++) {
            m1m[o] = fmaf(w1tm[o], p, m1m[o]);
            m1p[o] = fmaf(w1tp[o], p, m1p[o]);
        }
    }

    size_t base = (size_t)b * NC * HW + hw;
    for (int o = 0; o < NC; o++) {
        float am = b2mm[o], ap = b2pv[o];
        const float* r2m = w2mm + o * NC;
        const float* r2p = w2pv + o * NC;
#pragma unroll
        for (int m = 0; m < NC; m++) {
            am = fmaf(r2m[m], m1m[m], am);
            ap = fmaf(r2p[m], m1p[m], ap);
        }
        size_t off = base + (size_t)o * HW;
        t_mm[off]  = __float2bfloat16(am);
        t_pv[off]  = __float2bfloat16(ap);
        m1_mm[off] = __float2bfloat16(m1m[o]);
        m1_pv[off] = __float2bfloat16(m1p[o]);
    }
}

// ---------------- K2: dwconv5 + sigmoid + emb + where; write z and PhiL_pv ----------------
#define TR 16
__global__ void k2_attn(const bf16* __restrict__ t_mm, const bf16* __restrict__ t_pv,
                        const bf16* __restrict__ m1_mm, const bf16* __restrict__ m1_pv,
                        const float* __restrict__ x_pre,
                        const float* __restrict__ dwm, const float* __restrict__ dbm,
                        const float* __restrict__ dwp, const float* __restrict__ dbp,
                        bf16* __restrict__ z, bf16* __restrict__ philpv)
{
    __shared__ float sm[TR + 4][260];
    __shared__ float sp[TR + 4][260];

    int bid = blockIdx.x;
    int rt = bid & 15;
    int c  = (bid >> 4) % NC;
    int b  = (bid >> 4) / NC;
    int r0 = rt * TR;
    size_t cbase = ((size_t)b * NC + c) * HW;

    // stage t tiles (with 2-halo, zero-padded) into LDS as f32
    for (int e = threadIdx.x; e < (TR + 4) * 260; e += 256) {
        int r  = e / 260;
        int cc = e - r * 260;          // 0..259
        int gcol = cc - 2;
        int gr = r0 - 2 + r;
        float vm = 0.f, vp = 0.f;
        if (gr >= 0 && gr < 256 && gcol >= 0 && gcol < 256) {
            size_t o = cbase + (size_t)gr * 256 + gcol;
            vm = __bfloat162float(t_mm[o]);
            vp = __bfloat162float(t_pv[o]);
        }
        sm[r][cc] = vm;
        sp[r][cc] = vp;
    }
    __syncthreads();

    // depthwise weights for this channel (wave-uniform scalar loads)
    float wm[25], wp[25];
#pragma unroll
    for (int k = 0; k < 25; k++) { wm[k] = dwm[c * 25 + k]; wp[k] = dwp[c * 25 + k]; }
    float dbmc = dbm[c], dbpc = dbp[c];

    int w = threadIdx.x;   // 0..255 = output column
    for (int r = 0; r < TR; r++) {
        float accm = dbmc, accp = dbpc;
#pragma unroll
        for (int dy = 0; dy < 5; dy++) {
#pragma unroll
            for (int dx = 0; dx < 5; dx++) {
                accm = fmaf(wm[dy * 5 + dx], sm[r + dy][w + dx], accm);
                accp = fmaf(wp[dy * 5 + dx], sp[r + dy][w + dx], accp);
            }
        }
        float attm = 1.f / (1.f + __expf(-accm));
        float attp = 1.f / (1.f + __expf(-accp));
        size_t off = cbase + (size_t)(r0 + r) * 256 + w;
        float m1m = __bfloat162float(m1_mm[off]);
        float m1p = __bfloat162float(m1_pv[off]);
        float embm = m1m * attm + m1m;
        float embp = m1p * attp + m1p;
        if (embm == 0.f) embm = 1e-6f;
        if (embp == 0.f) embp = 1e-6f;
        z[off]      = __float2bfloat16(x_pre[off] * embm);
        philpv[off] = __float2bfloat16(embp);
    }
}

// ---------------- K3: temp = alpha * (y - A_op partial sums) ----------------
__global__ void k3_aop(const float* __restrict__ y, const bf16* __restrict__ z,
                       const float* __restrict__ alpha, float* __restrict__ temp)
{
    int idx = blockIdx.x * 256 + threadIdx.x;
    if (idx >= BATCH * ROWW * COLW) return;
    int col = idx % COLW;
    int bh  = idx / COLW;
    int h = bh & 255;
    int b = bh >> 8;
    int imin = (col > 255) ? ((col - 254) >> 1) : 0;
    int imax = min(27, col >> 1);
    float acc = y[idx];
    size_t base = (size_t)b * NC * HW + (size_t)h * 256 + col;
    for (int i = imin; i <= imax; i++) {
        // z[b][i][h][col-2i] = base + i*HW - 2i
        acc -= __bfloat162float(z[base + (size_t)i * (HW - 2)]);
    }
    temp[idx] = acc * alpha[col];
}

// ---------------- K4: out = x_pre + delta * temp_gathered * PhiL_pv ----------------
__global__ void k4_out(const float* __restrict__ x_pre, const bf16* __restrict__ philpv,
                       const float* __restrict__ temp, const float* __restrict__ delta,
                       float* __restrict__ out)
{
    int idx = blockIdx.x * 256 + threadIdx.x;   // < 29360128, exact grid
    int w = idx & 255;
    int rest = idx >> 8;
    int h = rest & 255;
    rest >>= 8;
    int i = rest % NC;
    int b = rest / NC;
    int col = w + 2 * i;
    float t = temp[((size_t)b * ROWW + h) * COLW + col];
    out[idx] = fmaf(delta[0] * t, __bfloat162float(philpv[idx]), x_pre[idx]);
}

// ---------------- launch ----------------
extern "C" void kernel_launch(void* const* d_in, const int* in_sizes, int n_in,
                              void* d_out, int out_size, void* d_ws, size_t ws_size,
                              hipStream_t stream)
{
    const float* y     = (const float*)d_in[0];
    const float* Phi   = (const float*)d_in[1];
    const float* x_pre = (const float*)d_in[2];
    const float* delta = (const float*)d_in[3];
    const float* mm_w1 = (const float*)d_in[4];
    const float* mm_b1 = (const float*)d_in[5];
    const float* mm_w2 = (const float*)d_in[6];
    const float* mm_b2 = (const float*)d_in[7];
    const float* mm_dw = (const float*)d_in[8];
    const float* mm_db = (const float*)d_in[9];
    const float* pv_w1 = (const float*)d_in[10];
    const float* pv_b1 = (const float*)d_in[11];
    const float* pv_w2 = (const float*)d_in[12];
    const float* pv_b2 = (const float*)d_in[13];
    const float* pv_dw = (const float*)d_in[14];
    const float* pv_db = (const float*)d_in[15];
    float* out = (float*)d_out;

    char* ws = (char*)d_ws;
    const size_t S = (size_t)BATCH * NC * HW * sizeof(bf16); // 58,720,256 B
    float* hdr    = (float*)ws;                 // w1t_mm[784] | w1t_pv[784] | alpha[310]
    bf16*  t_mm   = (bf16*)(ws + 8192);
    bf16*  t_pv   = (bf16*)(ws + 8192 + S);
    bf16*  m1_mm  = (bf16*)(ws + 8192 + 2 * S);
    bf16*  m1_pv  = (bf16*)(ws + 8192 + 3 * S);
    bf16*  zz     = (bf16*)(ws + 8192 + 4 * S);
    bf16*  philpv = (bf16*)(ws + 8192 + 5 * S);
    float* temp   = (float*)(ws + 8192 + 6 * S);

    k0_prep<<<1, 256, 0, stream>>>(mm_w1, pv_w1, hdr);
    k1_conv1x1<<<4096, 256, 0, stream>>>(Phi, mm_w2, pv_w2, mm_b1, mm_b2, pv_b1, pv_b2,
                                         hdr, t_mm, t_pv, m1_mm, m1_pv);
    k2_attn<<<BATCH * NC * (256 / TR), 256, 0, stream>>>(t_mm, t_pv, m1_mm, m1_pv, x_pre,
                                                         mm_dw, mm_db, pv_dw, pv_db, zz, philpv);
    k3_aop<<<(BATCH * ROWW * COLW + 255) / 256, 256, 0, stream>>>(y, zz, hdr + 1568, temp);
    k4_out<<<(BATCH * NC * HW) / 256, 256, 0, stream>>>(x_pre, philpv, temp, delta, out);
}

// Round 2
// 390.942 us; speedup vs baseline: 1.2211x; 1.2211x over previous
//
#include <hip/hip_runtime.h>
#include <hip/hip_bf16.h>
#include <cstdint>

#define NC 28
#define HW 65536   // 256*256
#define ROWW 256
#define COLW 310
#define BATCH 16

typedef __hip_bfloat16 bf16;

__device__ __forceinline__ float bflo(unsigned int u) { return __uint_as_float(u << 16); }
__device__ __forceinline__ float bfhi(unsigned int u) { return __uint_as_float(u & 0xffff0000u); }
__device__ __forceinline__ float sgpr(float x) {
    return __int_as_float(__builtin_amdgcn_readfirstlane(__float_as_int(x)));
}

// ---------------- K0: prep — transpose w1 matrices, compute alpha ----------------
__global__ void k0_prep(const float* __restrict__ w1mm, const float* __restrict__ w1pv,
                        float* __restrict__ hdr)
{
    int t = threadIdx.x;
    for (int e = t; e < 784; e += blockDim.x) {
        int c = e / 28, o = e - c * 28;
        hdr[e]       = w1mm[o * 28 + c];   // w1t_mm[c][o]
        hdr[784 + e] = w1pv[o * 28 + c];   // w1t_pv[c][o]
    }
    for (int col = t; col < COLW; col += blockDim.x) {
        int imin = (col > 255) ? ((col - 254) >> 1) : 0;
        int imax = min(27, col >> 1);
        hdr[1568 + col] = 1.0f / (float)(imax - imin + 1);
    }
}

// ---------------- K1: conv1x1 x2 for both branches, thread per pixel ----------------
__global__ void k1_conv1x1(const float* __restrict__ Phi,
                           const float* __restrict__ w2mm, const float* __restrict__ w2pv,
                           const float* __restrict__ b1mm, const float* __restrict__ b2mm,
                           const float* __restrict__ b1pv, const float* __restrict__ b2pv,
                           const float* __restrict__ hdr,
                           bf16* __restrict__ t_mm, bf16* __restrict__ t_pv,
                           bf16* __restrict__ m1_mm, bf16* __restrict__ m1_pv)
{
    int idx = blockIdx.x * 256 + threadIdx.x;   // 0 .. 1048575
    int b  = idx >> 16;                          // HW = 2^16
    int hw = idx & (HW - 1);
    const float* phi = Phi + (size_t)b * NC * HW + hw;

    float m1m[NC], m1p[NC];
#pragma unroll
    for (int o = 0; o < NC; o++) { m1m[o] = b1mm[o]; m1p[o] = b1pv[o]; }

    for (int c = 0; c < NC; c++) {
        float p = phi[(size_t)c * HW];
        const float* w1tm = hdr + c * NC;
        const float* w1tp = hdr + 784 + c * NC;
#pragma unroll
        for (int o = 0; o < NC; o++) {
            m1m[o] = fmaf(w1tm[o], p, m1m[o]);
            m1p[o] = fmaf(w1tp[o], p, m1p[o]);
        }
    }

    size_t base = (size_t)b * NC * HW + hw;
    for (int o = 0; o < NC; o++) {
        float am = b2mm[o], ap = b2pv[o];
        const float* r2m = w2mm + o * NC;
        const float* r2p = w2pv + o * NC;
#pragma unroll
        for (int m = 0; m < NC; m++) {
            am = fmaf(r2m[m], m1m[m], am);
            ap = fmaf(r2p[m], m1p[m], ap);
        }
        size_t off = base + (size_t)o * HW;
        t_mm[off]  = __float2bfloat16(am);
        t_pv[off]  = __float2bfloat16(ap);
        m1_mm[off] = __float2bfloat16(m1m[o]);
        m1_pv[off] = __float2bfloat16(m1p[o]);
    }
}

// ---------------- K2: dwconv5 + sigmoid + emb + where; write z and PhiL_pv ----------------
// Rolling-row register window; both branches packed as ushort2 in one LDS word.
#define TR 16
#define LROW 262   // padded LDS row length (in ushort2 words)

__global__ __launch_bounds__(256, 4) void k2_attn(
    const bf16* __restrict__ t_mm, const bf16* __restrict__ t_pv,
    const bf16* __restrict__ m1_mm, const bf16* __restrict__ m1_pv,
    const float* __restrict__ x_pre,
    const float* __restrict__ dwm, const float* __restrict__ dbm,
    const float* __restrict__ dwp, const float* __restrict__ dbp,
    bf16* __restrict__ z, bf16* __restrict__ philpv)
{
    __shared__ unsigned int st[(TR + 4) * LROW];   // 20*262*4 = 20,960 B

    int bid = blockIdx.x;
    int rt = bid & 15;
    int c  = (bid >> 4) % NC;
    int b  = (bid >> 4) / NC;
    int r0 = rt * TR;
    size_t cbase = ((size_t)b * NC + c) * HW;
    int tid = threadIdx.x;

    // zero the 4 halo columns (always zero: SAME padding) for all 20 rows
    if (tid < 80) {
        int r = tid >> 2, j = tid & 3;
        int cc = (j < 2) ? j : 256 + j;    // 0,1,258,259
        st[r * LROW + cc] = 0u;
    }

    // stage interior: 20 rows x 64 chunks of 4 cols; uint2 = 4 bf16 per array
    for (int slot = tid; slot < 20 * 64; slot += 256) {
        int r    = slot >> 6;
        int lane = slot & 63;
        int gr   = r0 - 2 + r;
        int gc   = lane * 4;
        unsigned int w0 = 0, w1 = 0, w2 = 0, w3 = 0;
        if (gr >= 0 && gr < 256) {
            size_t o = cbase + (size_t)gr * 256 + gc;
            uint2 am = *reinterpret_cast<const uint2*>(t_mm + o);
            uint2 ap = *reinterpret_cast<const uint2*>(t_pv + o);
            w0 = (am.x & 0xffffu)  | (ap.x << 16);
            w1 = (am.x >> 16)      | (ap.x & 0xffff0000u);
            w2 = (am.y & 0xffffu)  | (ap.y << 16);
            w3 = (am.y >> 16)      | (ap.y & 0xffff0000u);
        }
        int idx = r * LROW + 2 + gc;
        *reinterpret_cast<uint2*>(&st[idx])     = make_uint2(w0, w1);
        *reinterpret_cast<uint2*>(&st[idx + 2]) = make_uint2(w2, w3);
    }

    // depthwise weights -> SGPRs (block-uniform)
    float wmx[25], wpx[25];
#pragma unroll
    for (int k = 0; k < 25; k++) {
        wmx[k] = sgpr(dwm[c * 25 + k]);
        wpx[k] = sgpr(dwp[c * 25 + k]);
    }
    float dbmc = sgpr(dbm[c]), dbpc = sgpr(dbp[c]);

    __syncthreads();

    int w = tid;   // output column 0..255
    // rolling 5x5 window, both branches (x = mm, y = pv)
    float wxm[5][5], wxp[5][5];
#pragma unroll
    for (int rr = 0; rr < 4; rr++) {
#pragma unroll
        for (int dx = 0; dx < 5; dx++) {
            unsigned int u = st[rr * LROW + w + dx];
            wxm[rr][dx] = bflo(u);
            wxp[rr][dx] = bfhi(u);
        }
    }

#pragma unroll
    for (int r = 0; r < TR; r++) {
        // load incoming LDS row r+4 into window slot (r+4)%5
#pragma unroll
        for (int dx = 0; dx < 5; dx++) {
            unsigned int u = st[(r + 4) * LROW + w + dx];
            wxm[(r + 4) % 5][dx] = bflo(u);
            wxp[(r + 4) % 5][dx] = bfhi(u);
        }
        float accm = dbmc, accp = dbpc;
#pragma unroll
        for (int dy = 0; dy < 5; dy++) {
            const int wr = (r + dy) % 5;
#pragma unroll
            for (int dx = 0; dx < 5; dx++) {
                accm = fmaf(wmx[dy * 5 + dx], wxm[wr][dx], accm);
                accp = fmaf(wpx[dy * 5 + dx], wxp[wr][dx], accp);
            }
        }
        float attm = 1.f / (1.f + __expf(-accm));
        float attp = 1.f / (1.f + __expf(-accp));
        size_t off = cbase + (size_t)(r0 + r) * 256 + w;
        float m1m = __bfloat162float(m1_mm[off]);
        float m1p = __bfloat162float(m1_pv[off]);
        float embm = m1m * attm + m1m;
        float embp = m1p * attp + m1p;
        if (embm == 0.f) embm = 1e-6f;
        if (embp == 0.f) embp = 1e-6f;
        z[off]      = __float2bfloat16(x_pre[off] * embm);
        philpv[off] = __float2bfloat16(embp);
    }
}

// ---------------- K3: temp = alpha * (y - A_op partial sums) ----------------
__global__ void k3_aop(const float* __restrict__ y, const bf16* __restrict__ z,
                       const float* __restrict__ alpha, float* __restrict__ temp)
{
    int idx = blockIdx.x * 256 + threadIdx.x;
    if (idx >= BATCH * ROWW * COLW) return;
    int col = idx % COLW;
    int bh  = idx / COLW;
    int h = bh & 255;
    int b = bh >> 8;
    int imin = (col > 255) ? ((col - 254) >> 1) : 0;
    int imax = min(27, col >> 1);
    float acc = y[idx];
    size_t base = (size_t)b * NC * HW + (size_t)h * 256 + col;
    for (int i = imin; i <= imax; i++) {
        acc -= __bfloat162float(z[base + (size_t)i * (HW - 2)]);
    }
    temp[idx] = acc * alpha[col];
}

// ---------------- K4: out = x_pre + delta * temp_gathered * PhiL_pv ----------------
__global__ void k4_out(const float* __restrict__ x_pre, const bf16* __restrict__ philpv,
                       const float* __restrict__ temp, const float* __restrict__ delta,
                       float* __restrict__ out)
{
    int idx = blockIdx.x * 256 + threadIdx.x;   // exact grid
    int w = idx & 255;
    int rest = idx >> 8;
    int h = rest & 255;
    rest >>= 8;
    int i = rest % NC;
    int b = rest / NC;
    int col = w + 2 * i;
    float t = temp[((size_t)b * ROWW + h) * COLW + col];
    out[idx] = fmaf(delta[0] * t, __bfloat162float(philpv[idx]), x_pre[idx]);
}

// ---------------- launch ----------------
extern "C" void kernel_launch(void* const* d_in, const int* in_sizes, int n_in,
                              void* d_out, int out_size, void* d_ws, size_t ws_size,
                              hipStream_t stream)
{
    const float* y     = (const float*)d_in[0];
    const float* Phi   = (const float*)d_in[1];
    const float* x_pre = (const float*)d_in[2];
    const float* delta = (const float*)d_in[3];
    const float* mm_w1 = (const float*)d_in[4];
    const float* mm_b1 = (const float*)d_in[5];
    const float* mm_w2 = (const float*)d_in[6];
    const float* mm_b2 = (const float*)d_in[7];
    const float* mm_dw = (const float*)d_in[8];
    const float* mm_db = (const float*)d_in[9];
    const float* pv_w1 = (const float*)d_in[10];
    const float* pv_b1 = (const float*)d_in[11];
    const float* pv_w2 = (const float*)d_in[12];
    const float* pv_b2 = (const float*)d_in[13];
    const float* pv_dw = (const float*)d_in[14];
    const float* pv_db = (const float*)d_in[15];
    float* out = (float*)d_out;

    char* ws = (char*)d_ws;
    const size_t S = (size_t)BATCH * NC * HW * sizeof(bf16); // 58,720,256 B
    float* hdr    = (float*)ws;                 // w1t_mm[784] | w1t_pv[784] | alpha[310]
    bf16*  t_mm   = (bf16*)(ws + 8192);
    bf16*  t_pv   = (bf16*)(ws + 8192 + S);
    bf16*  m1_mm  = (bf16*)(ws + 8192 + 2 * S);
    bf16*  m1_pv  = (bf16*)(ws + 8192 + 3 * S);
    bf16*  zz     = (bf16*)(ws + 8192 + 4 * S);
    bf16*  philpv = (bf16*)(ws + 8192 + 5 * S);
    float* temp   = (float*)(ws + 8192 + 6 * S);

    k0_prep<<<1, 256, 0, stream>>>(mm_w1, pv_w1, hdr);
    k1_conv1x1<<<4096, 256, 0, stream>>>(Phi, mm_w2, pv_w2, mm_b1, mm_b2, pv_b1, pv_b2,
                                         hdr, t_mm, t_pv, m1_mm, m1_pv);
    k2_attn<<<BATCH * NC * (256 / TR), 256, 0, stream>>>(t_mm, t_pv, m1_mm, m1_pv, x_pre,
                                                         mm_dw, mm_db, pv_dw, pv_db, zz, philpv);
    k3_aop<<<(BATCH * ROWW * COLW + 255) / 256, 256, 0, stream>>>(y, zz, hdr + 1568, temp);
    k4_out<<<(BATCH * NC * HW) / 256, 256, 0, stream>>>(x_pre, philpv, temp, delta, out);
}

// Round 3
// 336.017 us; speedup vs baseline: 1.4207x; 1.1635x over previous
//
#include <hip/hip_runtime.h>
#include <hip/hip_bf16.h>
#include <cstdint>

#define NC 28
#define HW 65536   // 256*256
#define ROWW 256
#define COLW 310
#define BATCH 16

typedef __hip_bfloat16 bf16;

__device__ __forceinline__ float bflo(unsigned int u) { return __uint_as_float(u << 16); }
__device__ __forceinline__ float bfhi(unsigned int u) { return __uint_as_float(u & 0xffff0000u); }
__device__ __forceinline__ float sgpr(float x) {
    return __int_as_float(__builtin_amdgcn_readfirstlane(__float_as_int(x)));
}
__device__ __forceinline__ unsigned int pk2(float lo, float hi) {
    unsigned short l = __builtin_bit_cast(unsigned short, __float2bfloat16(lo));
    unsigned short h = __builtin_bit_cast(unsigned short, __float2bfloat16(hi));
    return (unsigned int)l | ((unsigned int)h << 16);
}

// ---------------- K0: prep — transpose w1 matrices, compute alpha ----------------
__global__ void k0_prep(const float* __restrict__ w1mm, const float* __restrict__ w1pv,
                        float* __restrict__ hdr)
{
    int t = threadIdx.x;
    for (int e = t; e < 784; e += blockDim.x) {
        int c = e / 28, o = e - c * 28;
        hdr[e]       = w1mm[o * 28 + c];   // w1t_mm[c][o]
        hdr[784 + e] = w1pv[o * 28 + c];   // w1t_pv[c][o]
    }
    for (int col = t; col < COLW; col += blockDim.x) {
        int imin = (col > 255) ? ((col - 254) >> 1) : 0;
        int imax = min(27, col >> 1);
        hdr[1568 + col] = 1.0f / (float)(imax - imin + 1);
    }
}

// ---------------- K1: conv1x1 x2 both branches; outputs PACKED uint32 ----------------
__global__ void k1_conv1x1(const float* __restrict__ Phi,
                           const float* __restrict__ w2mm, const float* __restrict__ w2pv,
                           const float* __restrict__ b1mm, const float* __restrict__ b2mm,
                           const float* __restrict__ b1pv, const float* __restrict__ b2pv,
                           const float* __restrict__ hdr,
                           unsigned int* __restrict__ t_pk, unsigned int* __restrict__ m1_pk)
{
    int idx = blockIdx.x * 256 + threadIdx.x;   // 0 .. 1048575
    int b  = idx >> 16;                          // HW = 2^16
    int hw = idx & (HW - 1);
    const float* phi = Phi + (size_t)b * NC * HW + hw;

    float m1m[NC], m1p[NC];
#pragma unroll
    for (int o = 0; o < NC; o++) { m1m[o] = b1mm[o]; m1p[o] = b1pv[o]; }

    for (int c = 0; c < NC; c++) {
        float p = phi[(size_t)c * HW];
        const float* w1tm = hdr + c * NC;
        const float* w1tp = hdr + 784 + c * NC;
#pragma unroll
        for (int o = 0; o < NC; o++) {
            m1m[o] = fmaf(w1tm[o], p, m1m[o]);
            m1p[o] = fmaf(w1tp[o], p, m1p[o]);
        }
    }

    size_t base = (size_t)b * NC * HW + hw;
    for (int o = 0; o < NC; o++) {
        float am = b2mm[o], ap = b2pv[o];
        const float* r2m = w2mm + o * NC;
        const float* r2p = w2pv + o * NC;
#pragma unroll
        for (int m = 0; m < NC; m++) {
            am = fmaf(r2m[m], m1m[m], am);
            ap = fmaf(r2p[m], m1p[m], ap);
        }
        size_t off = base + (size_t)o * HW;
        t_pk[off]  = pk2(am, ap);
        m1_pk[off] = pk2(m1m[o], m1p[o]);
    }
}

// ---------------- K2: dwconv5 + sigmoid + emb + where; rolling window in NAMED regs ----------------
#define TR 16
#define LROW 264   // words per LDS row; interior at [4..259], pads [2,3] and [260,261]; 16B-aligned

// load LDS row LR into window slot S (named registers)
#define LDROW(S, LR) do { \
    const unsigned int* rp_ = &st[(LR) * LROW + 2 + w]; \
    unsigned int u0_=rp_[0], u1_=rp_[1], u2_=rp_[2], u3_=rp_[3], u4_=rp_[4]; \
    m##S##0=bflo(u0_); p##S##0=bfhi(u0_); \
    m##S##1=bflo(u1_); p##S##1=bfhi(u1_); \
    m##S##2=bflo(u2_); p##S##2=bfhi(u2_); \
    m##S##3=bflo(u3_); p##S##3=bfhi(u3_); \
    m##S##4=bflo(u4_); p##S##4=bfhi(u4_); \
} while(0)

#define TAP5(S, B) \
    accm = fmaf(wmx[(B)+0], m##S##0, accm); accp = fmaf(wpx[(B)+0], p##S##0, accp); \
    accm = fmaf(wmx[(B)+1], m##S##1, accm); accp = fmaf(wpx[(B)+1], p##S##1, accp); \
    accm = fmaf(wmx[(B)+2], m##S##2, accm); accp = fmaf(wpx[(B)+2], p##S##2, accp); \
    accm = fmaf(wmx[(B)+3], m##S##3, accm); accp = fmaf(wpx[(B)+3], p##S##3, accp); \
    accm = fmaf(wmx[(B)+4], m##S##4, accm); accp = fmaf(wpx[(B)+4], p##S##4, accp);

#define CROW(R, S0,S1,S2,S3,S4) do { \
    float accm = dbmc, accp = dbpc; \
    TAP5(S0, 0) TAP5(S1, 5) TAP5(S2, 10) TAP5(S3, 15) TAP5(S4, 20) \
    float attm = __builtin_amdgcn_rcpf(1.f + __expf(-accm)); \
    float attp = __builtin_amdgcn_rcpf(1.f + __expf(-accp)); \
    size_t off_ = cbase + (size_t)(r0 + (R)) * 256 + w; \
    unsigned int mu_ = m1_pk[off_]; \
    float m1m_ = bflo(mu_), m1p_ = bfhi(mu_); \
    float embm_ = fmaf(m1m_, attm, m1m_); \
    float embp_ = fmaf(m1p_, attp, m1p_); \
    if (embm_ == 0.f) embm_ = 1e-6f; \
    if (embp_ == 0.f) embp_ = 1e-6f; \
    z[off_]      = __float2bfloat16(x_pre[off_] * embm_); \
    philpv[off_] = __float2bfloat16(embp_); \
} while(0)

__global__ __launch_bounds__(256, 4) void k2_attn(
    const unsigned int* __restrict__ t_pk, const unsigned int* __restrict__ m1_pk,
    const float* __restrict__ x_pre,
    const float* __restrict__ dwm, const float* __restrict__ dbm,
    const float* __restrict__ dwp, const float* __restrict__ dbp,
    bf16* __restrict__ z, bf16* __restrict__ philpv)
{
    __shared__ unsigned int st[(TR + 4) * LROW];   // 20*264*4 = 21,120 B

    int bid = blockIdx.x;
    int rt = bid & 15;
    int c  = (bid >> 4) % NC;
    int b  = (bid >> 4) / NC;
    int r0 = rt * TR;
    size_t cbase = ((size_t)b * NC + c) * HW;
    int tid = threadIdx.x;
    int lane = tid & 63;
    int wv = tid >> 6;

    // zero pad columns {2,3,260,261} for all 20 rows
    if (tid < 80) {
        int rr = tid >> 2, jj = tid & 3;
        st[rr * LROW + ((jj < 2) ? 2 + jj : 258 + jj)] = 0u;
    }

    // stage 20 rows: wave wv loads rows wv*5 .. wv*5+4 direct to LDS (1024B each)
#pragma unroll
    for (int j = 0; j < 5; j++) {
        int r = wv * 5 + j;
        int gr = r0 - 2 + r;
        if (gr >= 0 && gr < 256) {
            const unsigned int* gsrc = t_pk + cbase + (size_t)gr * 256 + lane * 4;
            __builtin_amdgcn_global_load_lds(
                (const __attribute__((address_space(1))) unsigned int*)gsrc,
                (__attribute__((address_space(3))) unsigned int*)&st[r * LROW + 4],
                16, 0, 0);
        } else {
            st[r * LROW + 4 + lane]       = 0u;
            st[r * LROW + 4 + 64 + lane]  = 0u;
            st[r * LROW + 4 + 128 + lane] = 0u;
            st[r * LROW + 4 + 192 + lane] = 0u;
        }
    }

    // depthwise weights -> SGPRs (block-uniform)
    float wmx[25], wpx[25];
#pragma unroll
    for (int k = 0; k < 25; k++) {
        wmx[k] = sgpr(dwm[c * 25 + k]);
        wpx[k] = sgpr(dwp[c * 25 + k]);
    }
    float dbmc = sgpr(dbm[c]), dbpc = sgpr(dbp[c]);

    __syncthreads();

    int w = tid;   // output column 0..255
    float m00,m01,m02,m03,m04, m10,m11,m12,m13,m14, m20,m21,m22,m23,m24,
          m30,m31,m32,m33,m34, m40,m41,m42,m43,m44;
    float p00,p01,p02,p03,p04, p10,p11,p12,p13,p14, p20,p21,p22,p23,p24,
          p30,p31,p32,p33,p34, p40,p41,p42,p43,p44;

    LDROW(0,0); LDROW(1,1); LDROW(2,2); LDROW(3,3);
    LDROW(4,4);  CROW(0, 0,1,2,3,4);
    LDROW(0,5);  CROW(1, 1,2,3,4,0);
    LDROW(1,6);  CROW(2, 2,3,4,0,1);
    LDROW(2,7);  CROW(3, 3,4,0,1,2);
    LDROW(3,8);  CROW(4, 4,0,1,2,3);
    LDROW(4,9);  CROW(5, 0,1,2,3,4);
    LDROW(0,10); CROW(6, 1,2,3,4,0);
    LDROW(1,11); CROW(7, 2,3,4,0,1);
    LDROW(2,12); CROW(8, 3,4,0,1,2);
    LDROW(3,13); CROW(9, 4,0,1,2,3);
    LDROW(4,14); CROW(10, 0,1,2,3,4);
    LDROW(0,15); CROW(11, 1,2,3,4,0);
    LDROW(1,16); CROW(12, 2,3,4,0,1);
    LDROW(2,17); CROW(13, 3,4,0,1,2);
    LDROW(3,18); CROW(14, 4,0,1,2,3);
    LDROW(4,19); CROW(15, 0,1,2,3,4);
}

// ---------------- K3: temp = alpha * (y - A_op partial sums) ----------------
__global__ void k3_aop(const float* __restrict__ y, const bf16* __restrict__ z,
                       const float* __restrict__ alpha, float* __restrict__ temp)
{
    int idx = blockIdx.x * 256 + threadIdx.x;
    if (idx >= BATCH * ROWW * COLW) return;
    int col = idx % COLW;
    int bh  = idx / COLW;
    int h = bh & 255;
    int b = bh >> 8;
    int imin = (col > 255) ? ((col - 254) >> 1) : 0;
    int imax = min(27, col >> 1);
    float acc = y[idx];
    size_t base = (size_t)b * NC * HW + (size_t)h * 256 + col;
    for (int i = imin; i <= imax; i++) {
        acc -= __bfloat162float(z[base + (size_t)i * (HW - 2)]);
    }
    temp[idx] = acc * alpha[col];
}

// ---------------- K4: out = x_pre + delta * temp_gathered * PhiL_pv (x2 vectorized) ----------------
__global__ void k4_out(const float* __restrict__ x_pre, const bf16* __restrict__ philpv,
                       const float* __restrict__ temp, const float* __restrict__ delta,
                       float* __restrict__ out)
{
    int idx2 = blockIdx.x * 256 + threadIdx.x;   // pair index; exact grid
    int wp = idx2 & 127;
    int rest = idx2 >> 7;
    int h = rest & 255; rest >>= 8;
    int i = rest % NC;
    int b = rest / NC;
    int w = wp * 2;
    int col = w + 2 * i;
    const float* trow = temp + ((size_t)(b * 256 + h)) * COLW + col;
    float t0 = trow[0], t1 = trow[1];
    size_t off = ((size_t)(b * NC + i)) * HW + (size_t)(h * 256 + w);
    unsigned int pu = *reinterpret_cast<const unsigned int*>(philpv + off);
    float2 xp = *reinterpret_cast<const float2*>(x_pre + off);
    float d = delta[0];
    float2 o2;
    o2.x = fmaf(d * t0, bflo(pu), xp.x);
    o2.y = fmaf(d * t1, bfhi(pu), xp.y);
    *reinterpret_cast<float2*>(out + off) = o2;
}

// ---------------- launch ----------------
extern "C" void kernel_launch(void* const* d_in, const int* in_sizes, int n_in,
                              void* d_out, int out_size, void* d_ws, size_t ws_size,
                              hipStream_t stream)
{
    const float* y     = (const float*)d_in[0];
    const float* Phi   = (const float*)d_in[1];
    const float* x_pre = (const float*)d_in[2];
    const float* delta = (const float*)d_in[3];
    const float* mm_w1 = (const float*)d_in[4];
    const float* mm_b1 = (const float*)d_in[5];
    const float* mm_w2 = (const float*)d_in[6];
    const float* mm_b2 = (const float*)d_in[7];
    const float* mm_dw = (const float*)d_in[8];
    const float* mm_db = (const float*)d_in[9];
    const float* pv_w1 = (const float*)d_in[10];
    const float* pv_b1 = (const float*)d_in[11];
    const float* pv_w2 = (const float*)d_in[12];
    const float* pv_b2 = (const float*)d_in[13];
    const float* pv_dw = (const float*)d_in[14];
    const float* pv_db = (const float*)d_in[15];
    float* out = (float*)d_out;

    char* ws = (char*)d_ws;
    const size_t A = (size_t)BATCH * NC * HW * 4;   // 117,440,512 B (uint array)
    float*        hdr    = (float*)ws;               // w1t_mm[784] | w1t_pv[784] | alpha[310]
    unsigned int* t_pk   = (unsigned int*)(ws + 8192);
    unsigned int* m1_pk  = (unsigned int*)(ws + 8192 + A);
    bf16*         zz     = (bf16*)(ws + 8192 + 2 * A);
    bf16*         philpv = (bf16*)(ws + 8192 + 2 * A + A / 2);
    float*        temp   = (float*)(ws + 8192 + 3 * A);

    k0_prep<<<1, 256, 0, stream>>>(mm_w1, pv_w1, hdr);
    k1_conv1x1<<<4096, 256, 0, stream>>>(Phi, mm_w2, pv_w2, mm_b1, mm_b2, pv_b1, pv_b2,
                                         hdr, t_pk, m1_pk);
    k2_attn<<<BATCH * NC * (256 / TR), 256, 0, stream>>>(t_pk, m1_pk, x_pre,
                                                         mm_dw, mm_db, pv_dw, pv_db, zz, philpv);
    k3_aop<<<(BATCH * ROWW * COLW + 255) / 256, 256, 0, stream>>>(y, zz, hdr + 1568, temp);
    k4_out<<<(BATCH * NC * HW / 2) / 256, 256, 0, stream>>>(x_pre, philpv, temp, delta, out);
}

// Round 4
// 305.917 us; speedup vs baseline: 1.5605x; 1.0984x over previous
//
#include <hip/hip_runtime.h>
#include <hip/hip_bf16.h>
#include <cstdint>

#define NC 28
#define HW 65536   // 256*256
#define ROWW 256
#define COLW 310
#define BATCH 16

typedef __hip_bfloat16 bf16;

__device__ __forceinline__ float bflo(unsigned int u) { return __uint_as_float(u << 16); }
__device__ __forceinline__ float bfhi(unsigned int u) { return __uint_as_float(u & 0xffff0000u); }
__device__ __forceinline__ float sgpr(float x) {
    return __int_as_float(__builtin_amdgcn_readfirstlane(__float_as_int(x)));
}
__device__ __forceinline__ unsigned int pk2(float lo, float hi) {
    unsigned short l = __builtin_bit_cast(unsigned short, __float2bfloat16(lo));
    unsigned short h = __builtin_bit_cast(unsigned short, __float2bfloat16(hi));
    return (unsigned int)l | ((unsigned int)h << 16);
}
__device__ __forceinline__ float2 upk(unsigned int u) {
    return make_float2(__uint_as_float(u << 16), __uint_as_float(u & 0xffff0000u));
}
// packed 2xf32 fma: acc = w*x + acc  (one VALU inst for both branches)
__device__ __forceinline__ void pkfma(float2& acc, const float2& w, const float2& x) {
    asm("v_pk_fma_f32 %0, %1, %2, %0" : "+v"(acc) : "s"(w), "v"(x));
}

// ---------------- K0: prep — transpose w1 matrices, compute alpha ----------------
__global__ void k0_prep(const float* __restrict__ w1mm, const float* __restrict__ w1pv,
                        float* __restrict__ hdr)
{
    int t = threadIdx.x;
    for (int e = t; e < 784; e += blockDim.x) {
        int c = e / 28, o = e - c * 28;
        hdr[e]       = w1mm[o * 28 + c];   // w1t_mm[c][o]
        hdr[784 + e] = w1pv[o * 28 + c];   // w1t_pv[c][o]
    }
    for (int col = t; col < COLW; col += blockDim.x) {
        int imin = (col > 255) ? ((col - 254) >> 1) : 0;
        int imax = min(27, col >> 1);
        hdr[1568 + col] = 1.0f / (float)(imax - imin + 1);
    }
}

// ---------------- K1: conv1x1 x2 both branches; outputs PACKED uint32 ----------------
__global__ void k1_conv1x1(const float* __restrict__ Phi,
                           const float* __restrict__ w2mm, const float* __restrict__ w2pv,
                           const float* __restrict__ b1mm, const float* __restrict__ b2mm,
                           const float* __restrict__ b1pv, const float* __restrict__ b2pv,
                           const float* __restrict__ hdr,
                           unsigned int* __restrict__ t_pk, unsigned int* __restrict__ m1_pk)
{
    int idx = blockIdx.x * 256 + threadIdx.x;   // 0 .. 1048575
    int b  = idx >> 16;                          // HW = 2^16
    int hw = idx & (HW - 1);
    const float* phi = Phi + (size_t)b * NC * HW + hw;

    float m1m[NC], m1p[NC];
#pragma unroll
    for (int o = 0; o < NC; o++) { m1m[o] = b1mm[o]; m1p[o] = b1pv[o]; }

    for (int c = 0; c < NC; c++) {
        float p = phi[(size_t)c * HW];
        const float* w1tm = hdr + c * NC;
        const float* w1tp = hdr + 784 + c * NC;
#pragma unroll
        for (int o = 0; o < NC; o++) {
            m1m[o] = fmaf(w1tm[o], p, m1m[o]);
            m1p[o] = fmaf(w1tp[o], p, m1p[o]);
        }
    }

    size_t base = (size_t)b * NC * HW + hw;
    for (int o = 0; o < NC; o++) {
        float am = b2mm[o], ap = b2pv[o];
        const float* r2m = w2mm + o * NC;
        const float* r2p = w2pv + o * NC;
#pragma unroll
        for (int m = 0; m < NC; m++) {
            am = fmaf(r2m[m], m1m[m], am);
            ap = fmaf(r2p[m], m1p[m], ap);
        }
        size_t off = base + (size_t)o * HW;
        t_pk[off]  = pk2(am, ap);
        m1_pk[off] = pk2(m1m[o], m1p[o]);
    }
}

// ---------------- K2: dwconv5 + sigmoid + emb + where; pk_fma, window in float2 regs ----------------
#define TR 16
#define LROW 264   // words per LDS row; interior at [4..259], pads [2,3] and [260,261]; 16B-aligned

// load LDS row LR (packed words) into window slot S as float2 pairs
#define LDROW(S, LR) do { \
    const unsigned int* rp_ = &st[(LR) * LROW + 2 + w]; \
    unsigned int u0_=rp_[0], u1_=rp_[1], u2_=rp_[2], u3_=rp_[3], u4_=rp_[4]; \
    W##S##0 = upk(u0_); W##S##1 = upk(u1_); W##S##2 = upk(u2_); \
    W##S##3 = upk(u3_); W##S##4 = upk(u4_); \
} while(0)

#define TAP5(S, B) \
    pkfma(acc, wq[(B)+0], W##S##0); \
    pkfma(acc, wq[(B)+1], W##S##1); \
    pkfma(acc, wq[(B)+2], W##S##2); \
    pkfma(acc, wq[(B)+3], W##S##3); \
    pkfma(acc, wq[(B)+4], W##S##4);

#define CROW(R, S0,S1,S2,S3,S4) do { \
    size_t off_ = cbase + (size_t)(r0 + (R)) * 256 + w; \
    unsigned int mu_ = m1_pk[off_]; \
    float xp_ = x_pre[off_]; \
    float2 acc = make_float2(dbmc, dbpc); \
    TAP5(S0, 0) TAP5(S1, 5) TAP5(S2, 10) TAP5(S3, 15) TAP5(S4, 20) \
    float attm = __builtin_amdgcn_rcpf(1.f + __expf(-acc.x)); \
    float attp = __builtin_amdgcn_rcpf(1.f + __expf(-acc.y)); \
    float m1m_ = bflo(mu_), m1p_ = bfhi(mu_); \
    float embm_ = fmaf(m1m_, attm, m1m_); \
    float embp_ = fmaf(m1p_, attp, m1p_); \
    if (embm_ == 0.f) embm_ = 1e-6f; \
    if (embp_ == 0.f) embp_ = 1e-6f; \
    z[off_]      = __float2bfloat16(xp_ * embm_); \
    philpv[off_] = __float2bfloat16(embp_); \
} while(0)

__global__ __launch_bounds__(256, 4) void k2_attn(
    const unsigned int* __restrict__ t_pk, const unsigned int* __restrict__ m1_pk,
    const float* __restrict__ x_pre,
    const float* __restrict__ dwm, const float* __restrict__ dbm,
    const float* __restrict__ dwp, const float* __restrict__ dbp,
    bf16* __restrict__ z, bf16* __restrict__ philpv)
{
    __shared__ unsigned int st[(TR + 4) * LROW];   // 20*264*4 = 21,120 B

    int bid = blockIdx.x;
    int rt = bid & 15;
    int c  = (bid >> 4) % NC;
    int b  = (bid >> 4) / NC;
    int r0 = rt * TR;
    size_t cbase = ((size_t)b * NC + c) * HW;
    int tid = threadIdx.x;
    int lane = tid & 63;
    int wv = tid >> 6;

    // zero pad columns {2,3,260,261} for all 20 rows
    if (tid < 80) {
        int rr = tid >> 2, jj = tid & 3;
        st[rr * LROW + ((jj < 2) ? 2 + jj : 258 + jj)] = 0u;
    }

    // stage 20 rows: wave wv loads rows wv*5 .. wv*5+4 direct to LDS (1024B each)
#pragma unroll
    for (int j = 0; j < 5; j++) {
        int r = wv * 5 + j;
        int gr = r0 - 2 + r;
        if (gr >= 0 && gr < 256) {
            const unsigned int* gsrc = t_pk + cbase + (size_t)gr * 256 + lane * 4;
            __builtin_amdgcn_global_load_lds(
                (const __attribute__((address_space(1))) unsigned int*)gsrc,
                (__attribute__((address_space(3))) unsigned int*)&st[r * LROW + 4],
                16, 0, 0);
        } else {
            st[r * LROW + 4 + lane]       = 0u;
            st[r * LROW + 4 + 64 + lane]  = 0u;
            st[r * LROW + 4 + 128 + lane] = 0u;
            st[r * LROW + 4 + 192 + lane] = 0u;
        }
    }

    // depthwise weights as (mm,pv) pairs -> SGPR pairs (block-uniform)
    float2 wq[25];
#pragma unroll
    for (int k = 0; k < 25; k++)
        wq[k] = make_float2(sgpr(dwm[c * 25 + k]), sgpr(dwp[c * 25 + k]));
    float dbmc = sgpr(dbm[c]), dbpc = sgpr(dbp[c]);

    __syncthreads();

    int w = tid;   // output column 0..255
    float2 W00,W01,W02,W03,W04, W10,W11,W12,W13,W14, W20,W21,W22,W23,W24,
           W30,W31,W32,W33,W34, W40,W41,W42,W43,W44;

    LDROW(0,0); LDROW(1,1); LDROW(2,2); LDROW(3,3);
    LDROW(4,4);  CROW(0, 0,1,2,3,4);
    LDROW(0,5);  CROW(1, 1,2,3,4,0);
    LDROW(1,6);  CROW(2, 2,3,4,0,1);
    LDROW(2,7);  CROW(3, 3,4,0,1,2);
    LDROW(3,8);  CROW(4, 4,0,1,2,3);
    LDROW(4,9);  CROW(5, 0,1,2,3,4);
    LDROW(0,10); CROW(6, 1,2,3,4,0);
    LDROW(1,11); CROW(7, 2,3,4,0,1);
    LDROW(2,12); CROW(8, 3,4,0,1,2);
    LDROW(3,13); CROW(9, 4,0,1,2,3);
    LDROW(4,14); CROW(10, 0,1,2,3,4);
    LDROW(0,15); CROW(11, 1,2,3,4,0);
    LDROW(1,16); CROW(12, 2,3,4,0,1);
    LDROW(2,17); CROW(13, 3,4,0,1,2);
    LDROW(3,18); CROW(14, 4,0,1,2,3);
    LDROW(4,19); CROW(15, 0,1,2,3,4);
}

// ---------------- K3: temp = alpha * (y - A_op partial sums) ----------------
__global__ void k3_aop(const float* __restrict__ y, const bf16* __restrict__ z,
                       const float* __restrict__ alpha, float* __restrict__ temp)
{
    int idx = blockIdx.x * 256 + threadIdx.x;
    if (idx >= BATCH * ROWW * COLW) return;
    int col = idx % COLW;
    int bh  = idx / COLW;
    int h = bh & 255;
    int b = bh >> 8;
    int imin = (col > 255) ? ((col - 254) >> 1) : 0;
    int imax = min(27, col >> 1);
    float acc = y[idx];
    size_t base = (size_t)b * NC * HW + (size_t)h * 256 + col;
    for (int i = imin; i <= imax; i++) {
        acc -= __bfloat162float(z[base + (size_t)i * (HW - 2)]);
    }
    temp[idx] = acc * alpha[col];
}

// ---------------- K4: out = x_pre + delta * temp_gathered * PhiL_pv (x4 vectorized) ----------------
__global__ void k4_out(const float* __restrict__ x_pre, const bf16* __restrict__ philpv,
                       const float* __restrict__ temp, const float* __restrict__ delta,
                       float* __restrict__ out)
{
    int idx4 = blockIdx.x * 256 + threadIdx.x;   // quad index; exact grid
    int wq4 = idx4 & 63;
    int rest = idx4 >> 6;
    int h = rest & 255; rest >>= 8;
    int i = rest % NC;
    int b = rest / NC;
    int w = wq4 * 4;
    int col = w + 2 * i;
    const float* trow = temp + ((size_t)(b * 256 + h)) * COLW + col;
    float t0 = trow[0], t1 = trow[1], t2 = trow[2], t3 = trow[3];
    size_t off = ((size_t)(b * NC + i)) * HW + (size_t)(h * 256 + w);
    uint2 pu = *reinterpret_cast<const uint2*>(philpv + off);
    float4 xp = *reinterpret_cast<const float4*>(x_pre + off);
    float d = delta[0];
    float4 o4;
    o4.x = fmaf(d * t0, bflo(pu.x), xp.x);
    o4.y = fmaf(d * t1, bfhi(pu.x), xp.y);
    o4.z = fmaf(d * t2, bflo(pu.y), xp.z);
    o4.w = fmaf(d * t3, bfhi(pu.y), xp.w);
    *reinterpret_cast<float4*>(out + off) = o4;
}

// ---------------- launch ----------------
extern "C" void kernel_launch(void* const* d_in, const int* in_sizes, int n_in,
                              void* d_out, int out_size, void* d_ws, size_t ws_size,
                              hipStream_t stream)
{
    const float* y     = (const float*)d_in[0];
    const float* Phi   = (const float*)d_in[1];
    const float* x_pre = (const float*)d_in[2];
    const float* delta = (const float*)d_in[3];
    const float* mm_w1 = (const float*)d_in[4];
    const float* mm_b1 = (const float*)d_in[5];
    const float* mm_w2 = (const float*)d_in[6];
    const float* mm_b2 = (const float*)d_in[7];
    const float* mm_dw = (const float*)d_in[8];
    const float* mm_db = (const float*)d_in[9];
    const float* pv_w1 = (const float*)d_in[10];
    const float* pv_b1 = (const float*)d_in[11];
    const float* pv_w2 = (const float*)d_in[12];
    const float* pv_b2 = (const float*)d_in[13];
    const float* pv_dw = (const float*)d_in[14];
    const float* pv_db = (const float*)d_in[15];
    float* out = (float*)d_out;

    char* ws = (char*)d_ws;
    const size_t A = (size_t)BATCH * NC * HW * 4;   // 117,440,512 B (uint array)
    float*        hdr    = (float*)ws;               // w1t_mm[784] | w1t_pv[784] | alpha[310]
    unsigned int* t_pk   = (unsigned int*)(ws + 8192);
    unsigned int* m1_pk  = (unsigned int*)(ws + 8192 + A);
    bf16*         zz     = (bf16*)(ws + 8192 + 2 * A);
    bf16*         philpv = (bf16*)(ws + 8192 + 2 * A + A / 2);
    float*        temp   = (float*)(ws + 8192 + 3 * A);

    k0_prep<<<1, 256, 0, stream>>>(mm_w1, pv_w1, hdr);
    k1_conv1x1<<<4096, 256, 0, stream>>>(Phi, mm_w2, pv_w2, mm_b1, mm_b2, pv_b1, pv_b2,
                                         hdr, t_pk, m1_pk);
    k2_attn<<<BATCH * NC * (256 / TR), 256, 0, stream>>>(t_pk, m1_pk, x_pre,
                                                         mm_dw, mm_db, pv_dw, pv_db, zz, philpv);
    k3_aop<<<(BATCH * ROWW * COLW + 255) / 256, 256, 0, stream>>>(y, zz, hdr + 1568, temp);
    k4_out<<<(BATCH * NC * HW / 4) / 256, 256, 0, stream>>>(x_pre, philpv, temp, delta, out);
}